// Round 1
// baseline (973.918 us; speedup 1.0000x reference)
//
#include <hip/hip_runtime.h>

// NBVLoss: weighted BCE reduction over 4096x32768 fp32.
//   total = 10 * sum_{t==1} min(-log(p),100) + 1 * sum_{t==0} min(-log(1-p),100)
// Memory-bound: 1.074 GB read -> ~170us floor at 6.3 TB/s.

#define LAMBDA_FOR1 10.0f

__device__ __forceinline__ float bce_term(float p, float t) {
    // t is exactly 0.0f or 1.0f per the reference's bernoulli->float input.
    bool is_one = (t != 0.0f);
    float x = is_one ? p : (1.0f - p);          // 1-p exact for p>=0.5 (Sterbenz)
    float l = fminf(-__logf(x), 100.0f);        // -log clamped at 100 (handles x==0 -> inf)
    return is_one ? (LAMBDA_FOR1 * l) : l;
}

__global__ __launch_bounds__(256) void nbv_loss_kernel(
        const float4* __restrict__ pred4,
        const float4* __restrict__ tgt4,
        float* __restrict__ out,
        int n4, int tail_base, int tail_count) {
    float acc = 0.0f;
    const int stride = gridDim.x * blockDim.x;
    for (int i = blockIdx.x * blockDim.x + threadIdx.x; i < n4; i += stride) {
        float4 p = pred4[i];
        float4 t = tgt4[i];
        acc += bce_term(p.x, t.x);
        acc += bce_term(p.y, t.y);
        acc += bce_term(p.z, t.z);
        acc += bce_term(p.w, t.w);
    }
    // Scalar tail (n not divisible by 4) — handled by block 0 only.
    if (blockIdx.x == 0 && (int)threadIdx.x < tail_count) {
        const float* pred = (const float*)pred4;
        const float* tgt  = (const float*)tgt4;
        int i = tail_base + threadIdx.x;
        acc += bce_term(pred[i], tgt[i]);
    }

    // Wave (64-lane) shuffle reduction.
#pragma unroll
    for (int off = 32; off > 0; off >>= 1)
        acc += __shfl_down(acc, off, 64);

    __shared__ float wave_sum[4];   // 256 threads = 4 waves
    const int lane = threadIdx.x & 63;
    const int wid  = threadIdx.x >> 6;
    if (lane == 0) wave_sum[wid] = acc;
    __syncthreads();
    if (threadIdx.x == 0) {
        float s = wave_sum[0] + wave_sum[1] + wave_sum[2] + wave_sum[3];
        atomicAdd(out, s);          // one device-scope atomic per block (4096 total)
    }
}

extern "C" void kernel_launch(void* const* d_in, const int* in_sizes, int n_in,
                              void* d_out, int out_size, void* d_ws, size_t ws_size,
                              hipStream_t stream) {
    const float* pred = (const float*)d_in[0];   // predictions, fp32
    const float* tgt  = (const float*)d_in[1];   // target, fp32 (0.0 or 1.0)
    float* out = (float*)d_out;                  // scalar fp32 result

    const int n  = in_sizes[0];                  // 134,217,728 (fits in int32)
    const int n4 = n >> 2;
    const int tail_base  = n4 << 2;
    const int tail_count = n - tail_base;

    // d_out is poisoned to 0xAA before every timed launch — zero it ourselves.
    hipMemsetAsync(d_out, 0, sizeof(float), stream);

    const int block = 256;
    const int grid  = 4096;                      // 1M threads, 32 float4 iters each
    nbv_loss_kernel<<<grid, block, 0, stream>>>(
        (const float4*)pred, (const float4*)tgt, out, n4, tail_base, tail_count);
}